// Round 2
// baseline (143.145 us; speedup 1.0000x reference)
//
#include <hip/hip_runtime.h>
#include <math.h>

#define HSZ 2048
#define OSZ 1024
#define NGATE 8192  // 4*HSZ

__device__ __forceinline__ float wave_reduce_sum(float v) {
    #pragma unroll
    for (int off = 32; off > 0; off >>= 1)
        v += __shfl_down(v, off, 64);
    return v;
}

struct PreArgs {
    const float* x;      // 1024
    const float* h0; const float* h1; const float* h2; const float* h3; const float* h4;
    const float* Wih1;   // 8192x1024
    const float* W0; const float* W1; const float* W2; const float* W3; const float* W4; // Whh_k 8192x2048
    const float* bi0; const float* bi1; const float* bi2; const float* bi3; const float* bi4;
    const float* bh0; const float* bh1; const float* bh2; const float* bh3; const float* bh4;
    float* pre;          // ws, 5*8192
};

// 2048 blocks x 256 threads = 8192 waves; wave g computes gate row g for ALL 5 layers.
// pre[k*8192+g] = Whh_k[g,:]·h_k + bih_k[g] + bhh_k[g] (+ Wih1[g,:]·x for k=0)
__global__ __launch_bounds__(256) void k_pre(PreArgs a) {
    const int g    = blockIdx.x * 4 + (threadIdx.x >> 6);  // 0..8191
    const int lane = threadIdx.x & 63;

    const float* Whh[5] = {a.W0, a.W1, a.W2, a.W3, a.W4};
    const float* hs[5]  = {a.h0, a.h1, a.h2, a.h3, a.h4};
    const float* bi[5]  = {a.bi0, a.bi1, a.bi2, a.bi3, a.bi4};
    const float* bh[5]  = {a.bh0, a.bh1, a.bh2, a.bh3, a.bh4};

    float lsum[5];
    #pragma unroll
    for (int k = 0; k < 5; ++k) {
        const float4* Wrow = (const float4*)(Whh[k] + (size_t)g * HSZ);
        const float4* hv   = (const float4*)hs[k];
        float s = 0.f;
        #pragma unroll
        for (int it = 0; it < 8; ++it) {
            float4 wv = Wrow[it * 64 + lane];
            float4 h4 = hv[it * 64 + lane];
            s += wv.x * h4.x + wv.y * h4.y + wv.z * h4.z + wv.w * h4.w;
        }
        lsum[k] = s;
    }
    {   // layer-1 input term
        const float4* Wr = (const float4*)(a.Wih1 + (size_t)g * OSZ);
        const float4* xv = (const float4*)a.x;
        float s = 0.f;
        #pragma unroll
        for (int it = 0; it < 4; ++it) {
            float4 wv = Wr[it * 64 + lane];
            float4 x4 = xv[it * 64 + lane];
            s += wv.x * x4.x + wv.y * x4.y + wv.z * x4.z + wv.w * x4.w;
        }
        lsum[0] += s;
    }

    // interleaved wave reductions (5 independent chains share the 6 steps)
    #pragma unroll
    for (int off = 32; off > 0; off >>= 1) {
        #pragma unroll
        for (int k = 0; k < 5; ++k)
            lsum[k] += __shfl_down(lsum[k], off, 64);
    }
    if (lane == 0) {
        #pragma unroll
        for (int k = 0; k < 5; ++k)
            a.pre[k * NGATE + g] = lsum[k] + bi[k][g] + bh[k][g];
    }
}

// gates[g] += Wih[g,:] · (ya [+ yb]) — one wave per row, 8192 rows
__global__ __launch_bounds__(256) void k_gatex(const float* __restrict__ Wih,
                                               const float* __restrict__ ya,
                                               const float* __restrict__ yb,
                                               float* __restrict__ gates) {
    const int w    = blockIdx.x * 4 + (threadIdx.x >> 6);  // 0..8191
    const int lane = threadIdx.x & 63;
    const float4* Wrow = (const float4*)(Wih + (size_t)w * OSZ);
    const float4* A = (const float4*)ya;
    const float4* B = (const float4*)yb;
    float sum = 0.f;
    #pragma unroll
    for (int it = 0; it < 4; ++it) {
        float4 wv = Wrow[it * 64 + lane];
        float4 av = A[it * 64 + lane];
        if (B) {
            float4 bv = B[it * 64 + lane];
            av.x += bv.x; av.y += bv.y; av.z += bv.z; av.w += bv.w;
        }
        sum += wv.x * av.x + wv.y * av.y + wv.z * av.z + wv.w * av.w;
    }
    sum = wave_reduce_sum(sum);
    if (lane == 0)
        gates[w] += sum;
}

// Fused LSTM-cell + head: block recomputes h into LDS from gates/c, block 0 also
// writes hn/cn to global; then 4 rows of Wout per block (1 row/wave).
__global__ __launch_bounds__(256) void k_head2(const float* __restrict__ gates,
                                               const float* __restrict__ c_in,
                                               float* __restrict__ hn,
                                               float* __restrict__ cn,
                                               const float* __restrict__ Wout,
                                               const float* __restrict__ bout,
                                               float* __restrict__ y) {
    __shared__ float sh[HSZ];
    const int t = threadIdx.x;

    #pragma unroll
    for (int r = 0; r < 2; ++r) {
        const int idx = r * 256 + t;  // float4 index, 0..511
        float4 gi4 = ((const float4*)gates)[idx];
        float4 gf4 = ((const float4*)(gates + HSZ))[idx];
        float4 gg4 = ((const float4*)(gates + 2 * HSZ))[idx];
        float4 go4 = ((const float4*)(gates + 3 * HSZ))[idx];
        float4 c4  = ((const float4*)c_in)[idx];
        float hv[4], cv[4];
        const float gi[4] = {gi4.x, gi4.y, gi4.z, gi4.w};
        const float gf[4] = {gf4.x, gf4.y, gf4.z, gf4.w};
        const float gg[4] = {gg4.x, gg4.y, gg4.z, gg4.w};
        const float go[4] = {go4.x, go4.y, go4.z, go4.w};
        const float cc[4] = {c4.x, c4.y, c4.z, c4.w};
        #pragma unroll
        for (int e = 0; e < 4; ++e) {
            float i = 1.f / (1.f + expf(-gi[e]));
            float f = 1.f / (1.f + expf(-gf[e]));
            float gv = tanhf(gg[e]);
            float o = 1.f / (1.f + expf(-go[e]));
            float cnew = f * cc[e] + i * gv;
            hv[e] = o * tanhf(cnew);
            cv[e] = cnew;
        }
        const int j = idx * 4;
        sh[j] = hv[0]; sh[j + 1] = hv[1]; sh[j + 2] = hv[2]; sh[j + 3] = hv[3];
        if (blockIdx.x == 0) {
            float4* hn4 = (float4*)hn;
            float4* cn4 = (float4*)cn;
            hn4[idx] = make_float4(hv[0], hv[1], hv[2], hv[3]);
            cn4[idx] = make_float4(cv[0], cv[1], cv[2], cv[3]);
        }
    }
    __syncthreads();

    const int row  = blockIdx.x * 4 + (t >> 6);  // 0..1023
    const int lane = t & 63;
    const float4* Wrow = (const float4*)(Wout + (size_t)row * HSZ);
    const float4* hv4  = (const float4*)sh;
    float sum = 0.f;
    #pragma unroll
    for (int it = 0; it < 8; ++it) {
        float4 wv = Wrow[it * 64 + lane];
        float4 h4 = hv4[it * 64 + lane];
        sum += wv.x * h4.x + wv.y * h4.y + wv.z * h4.z + wv.w * h4.w;
    }
    sum = wave_reduce_sum(sum);
    if (lane == 0)
        y[row] = sum + bout[row];
}

// softmax over 1024 logits, single block of 1024 threads
__global__ __launch_bounds__(1024) void k_softmax(const float* __restrict__ logits,
                                                  float* __restrict__ out) {
    __shared__ float sm[16];
    __shared__ float ss[16];
    const int t = threadIdx.x;
    const int lane = t & 63;
    const int wid = t >> 6;
    float v = logits[t];
    float m = v;
    #pragma unroll
    for (int off = 32; off > 0; off >>= 1)
        m = fmaxf(m, __shfl_down(m, off, 64));
    if (lane == 0) sm[wid] = m;
    __syncthreads();
    if (t == 0) {
        float mm = sm[0];
        for (int i = 1; i < 16; ++i) mm = fmaxf(mm, sm[i]);
        sm[0] = mm;
    }
    __syncthreads();
    m = sm[0];
    float e = expf(v - m);
    float s = wave_reduce_sum(e);
    if (lane == 0) ss[wid] = s;
    __syncthreads();
    if (t == 0) {
        float tt = 0.f;
        for (int i = 0; i < 16; ++i) tt += ss[i];
        ss[0] = tt;
    }
    __syncthreads();
    out[t] = e / ss[0];
}

extern "C" void kernel_launch(void* const* d_in, const int* in_sizes, int n_in,
                              void* d_out, int out_size, void* d_ws, size_t ws_size,
                              hipStream_t stream) {
    const float* x = (const float*)d_in[0];
    const float* h[5]; const float* c[5];
    for (int k = 0; k < 5; ++k) {
        h[k] = (const float*)d_in[1 + 2 * k];
        c[k] = (const float*)d_in[2 + 2 * k];
    }
    const float* Wih[5]; const float* Whh[5]; const float* bih[5]; const float* bhh[5];
    for (int k = 0; k < 5; ++k) {
        Wih[k] = (const float*)d_in[11 + 4 * k];
        Whh[k] = (const float*)d_in[12 + 4 * k];
        bih[k] = (const float*)d_in[13 + 4 * k];
        bhh[k] = (const float*)d_in[14 + 4 * k];
    }
    const float* Wout = (const float*)d_in[31];
    const float* bout = (const float*)d_in[32];

    float* out = (float*)d_out;              // [0,1024) softmax out
    float* hn[5]; float* cn[5];
    for (int k = 0; k < 5; ++k) {
        hn[k] = out + 1024 + k * 4096;
        cn[k] = hn[k] + 2048;
    }

    float* ws  = (float*)d_ws;
    float* pre = ws;             // 5*8192 floats
    float* y   = ws + 5 * NGATE; // 5*1024 floats

    PreArgs pa;
    pa.x = x;
    pa.h0 = h[0]; pa.h1 = h[1]; pa.h2 = h[2]; pa.h3 = h[3]; pa.h4 = h[4];
    pa.Wih1 = Wih[0];
    pa.W0 = Whh[0]; pa.W1 = Whh[1]; pa.W2 = Whh[2]; pa.W3 = Whh[3]; pa.W4 = Whh[4];
    pa.bi0 = bih[0]; pa.bi1 = bih[1]; pa.bi2 = bih[2]; pa.bi3 = bih[3]; pa.bi4 = bih[4];
    pa.bh0 = bhh[0]; pa.bh1 = bhh[1]; pa.bh2 = bhh[2]; pa.bh3 = bhh[3]; pa.bh4 = bhh[4];
    pa.pre = pre;

    // All recurrent (Whh@h) GEMVs + Wih1@x: ~352 MB of streaming, 1 wave per gate row x 5 layers
    k_pre<<<2048, 256, 0, stream>>>(pa);

    // layer 1
    k_head2<<<256, 256, 0, stream>>>(pre, c[0], hn[0], cn[0], Wout, bout, y);
    // layer 2 (input y1)
    k_gatex<<<2048, 256, 0, stream>>>(Wih[1], y, nullptr, pre + NGATE);
    k_head2<<<256, 256, 0, stream>>>(pre + NGATE, c[1], hn[1], cn[1], Wout, bout, y + 1024);
    // layer 3 (input y2+y1)
    k_gatex<<<2048, 256, 0, stream>>>(Wih[2], y + 1024, y, pre + 2 * NGATE);
    k_head2<<<256, 256, 0, stream>>>(pre + 2 * NGATE, c[2], hn[2], cn[2], Wout, bout, y + 2048);
    // layer 4 (input y3+y2)
    k_gatex<<<2048, 256, 0, stream>>>(Wih[3], y + 2048, y + 1024, pre + 3 * NGATE);
    k_head2<<<256, 256, 0, stream>>>(pre + 3 * NGATE, c[3], hn[3], cn[3], Wout, bout, y + 3072);
    // layer 5 (input y4+y3)
    k_gatex<<<2048, 256, 0, stream>>>(Wih[4], y + 3072, y + 2048, pre + 4 * NGATE);
    k_head2<<<256, 256, 0, stream>>>(pre + 4 * NGATE, c[4], hn[4], cn[4], Wout, bout, y + 4096);
    // softmax -> out
    k_softmax<<<1, 1024, 0, stream>>>(y + 4096, out);
}

// Round 3
// 135.213 us; speedup vs baseline: 1.0587x; 1.0587x over previous
//
#include <hip/hip_runtime.h>
#include <math.h>

#define HSZ 2048
#define OSZ 1024
#define NGATE 8192  // 4*HSZ

__device__ __forceinline__ float wave_reduce_sum(float v) {
    #pragma unroll
    for (int off = 32; off > 0; off >>= 1)
        v += __shfl_down(v, off, 64);
    return v;
}

struct PreArgs {
    const float* x;      // 1024
    const float* h0; const float* h1; const float* h2; const float* h3; const float* h4;
    const float* Wih1;   // 8192x1024
    const float* W0; const float* W1; const float* W2; const float* W3; const float* W4; // Whh_k 8192x2048
    const float* bi0; const float* bi1; const float* bi2; const float* bi3; const float* bi4;
    const float* bh0; const float* bh1; const float* bh2; const float* bh3; const float* bh4;
    float* pre;          // ws, 5*8192
};

// 2048 blocks x 256 threads = 8192 waves; wave g computes gate row g for ALL 5 layers.
// Register-tiled + double-buffered across layers: 8 outstanding 1KB loads while
// the previous layer's dot-product retires (MLP fix for the 1.5 TB/s plateau).
// pre[k*8192+g] = Whh_k[g,:]·h_k + bih_k[g] + bhh_k[g] (+ Wih1[g,:]·x for k=0)
__global__ __launch_bounds__(256) void k_pre(PreArgs a) {
    const int g    = blockIdx.x * 4 + (threadIdx.x >> 6);  // 0..8191
    const int lane = threadIdx.x & 63;

    const float* Whh[5] = {a.W0, a.W1, a.W2, a.W3, a.W4};
    const float* hs[5]  = {a.h0, a.h1, a.h2, a.h3, a.h4};
    const float* bi[5]  = {a.bi0, a.bi1, a.bi2, a.bi3, a.bi4};
    const float* bh[5]  = {a.bh0, a.bh1, a.bh2, a.bh3, a.bh4};

    float4 wbuf[2][8];   // fully unrolled -> static indices -> stays in VGPRs
    float4 wx[4];

    // prologue: layer-0 weight row + Wih1 row in flight together
    {
        const float4* Wrow = (const float4*)(Whh[0] + (size_t)g * HSZ);
        #pragma unroll
        for (int it = 0; it < 8; ++it) wbuf[0][it] = Wrow[it * 64 + lane];
        const float4* Wr = (const float4*)(a.Wih1 + (size_t)g * OSZ);
        #pragma unroll
        for (int it = 0; it < 4; ++it) wx[it] = Wr[it * 64 + lane];
    }

    float lsum[5];
    #pragma unroll
    for (int k = 0; k < 5; ++k) {
        // prefetch next layer's full row while we consume this one
        if (k < 4) {
            const float4* Wn = (const float4*)(Whh[k + 1] + (size_t)g * HSZ);
            #pragma unroll
            for (int it = 0; it < 8; ++it) wbuf[(k + 1) & 1][it] = Wn[it * 64 + lane];
        }
        const float4* hv = (const float4*)hs[k];
        float s = 0.f;
        #pragma unroll
        for (int it = 0; it < 8; ++it) {
            float4 wv = wbuf[k & 1][it];
            float4 h4 = hv[it * 64 + lane];
            s += wv.x * h4.x + wv.y * h4.y + wv.z * h4.z + wv.w * h4.w;
        }
        if (k == 0) {
            const float4* xv = (const float4*)a.x;
            #pragma unroll
            for (int it = 0; it < 4; ++it) {
                float4 x4 = xv[it * 64 + lane];
                s += wx[it].x * x4.x + wx[it].y * x4.y + wx[it].z * x4.z + wx[it].w * x4.w;
            }
        }
        lsum[k] = s;
    }

    // interleaved wave reductions (5 independent chains share the 6 steps)
    #pragma unroll
    for (int off = 32; off > 0; off >>= 1) {
        #pragma unroll
        for (int k = 0; k < 5; ++k)
            lsum[k] += __shfl_down(lsum[k], off, 64);
    }
    if (lane == 0) {
        #pragma unroll
        for (int k = 0; k < 5; ++k)
            a.pre[k * NGATE + g] = lsum[k] + bi[k][g] + bh[k][g];
    }
}

// gates[g] += Wih[g,:] · (ya [+ yb]) — one wave per row, 8192 rows
__global__ __launch_bounds__(256) void k_gatex(const float* __restrict__ Wih,
                                               const float* __restrict__ ya,
                                               const float* __restrict__ yb,
                                               float* __restrict__ gates) {
    const int w    = blockIdx.x * 4 + (threadIdx.x >> 6);  // 0..8191
    const int lane = threadIdx.x & 63;
    const float4* Wrow = (const float4*)(Wih + (size_t)w * OSZ);
    const float4* A = (const float4*)ya;
    const float4* B = (const float4*)yb;
    float sum = 0.f;
    #pragma unroll
    for (int it = 0; it < 4; ++it) {
        float4 wv = Wrow[it * 64 + lane];
        float4 av = A[it * 64 + lane];
        if (B) {
            float4 bv = B[it * 64 + lane];
            av.x += bv.x; av.y += bv.y; av.z += bv.z; av.w += bv.w;
        }
        sum += wv.x * av.x + wv.y * av.y + wv.z * av.z + wv.w * av.w;
    }
    sum = wave_reduce_sum(sum);
    if (lane == 0)
        gates[w] += sum;
}

// LSTM cell elementwise: 2048 threads
__global__ __launch_bounds__(256) void k_cell(const float* __restrict__ gates,
                                              const float* __restrict__ c_in,
                                              float* __restrict__ hn,
                                              float* __restrict__ cn) {
    const int j = blockIdx.x * 256 + threadIdx.x;  // grid 8 -> 0..2047
    float gi = gates[j];
    float gf = gates[HSZ + j];
    float gg = gates[2 * HSZ + j];
    float go = gates[3 * HSZ + j];
    float i = 1.f / (1.f + expf(-gi));
    float f = 1.f / (1.f + expf(-gf));
    float g = tanhf(gg);
    float o = 1.f / (1.f + expf(-go));
    float c = c_in[j];
    float cnew = f * c + i * g;
    float hnew = o * tanhf(cnew);
    cn[j] = cnew;
    hn[j] = hnew;
}

// y[j] = Wout[j,:] · h + bout[j] — one wave per row, 1024 rows
__global__ __launch_bounds__(256) void k_head(const float* __restrict__ Wout,
                                              const float* __restrict__ bout,
                                              const float* __restrict__ h,
                                              float* __restrict__ y) {
    const int w    = blockIdx.x * 4 + (threadIdx.x >> 6);  // 0..1023
    const int lane = threadIdx.x & 63;
    const float4* Wrow = (const float4*)(Wout + (size_t)w * HSZ);
    const float4* hv   = (const float4*)h;
    float sum = 0.f;
    #pragma unroll
    for (int it = 0; it < 8; ++it) {
        float4 wv = Wrow[it * 64 + lane];
        float4 h4 = hv[it * 64 + lane];
        sum += wv.x * h4.x + wv.y * h4.y + wv.z * h4.z + wv.w * h4.w;
    }
    sum = wave_reduce_sum(sum);
    if (lane == 0)
        y[w] = sum + bout[w];
}

// softmax over 1024 logits, single block of 1024 threads
__global__ __launch_bounds__(1024) void k_softmax(const float* __restrict__ logits,
                                                  float* __restrict__ out) {
    __shared__ float sm[16];
    __shared__ float ss[16];
    const int t = threadIdx.x;
    const int lane = t & 63;
    const int wid = t >> 6;
    float v = logits[t];
    float m = v;
    #pragma unroll
    for (int off = 32; off > 0; off >>= 1)
        m = fmaxf(m, __shfl_down(m, off, 64));
    if (lane == 0) sm[wid] = m;
    __syncthreads();
    if (t == 0) {
        float mm = sm[0];
        for (int i = 1; i < 16; ++i) mm = fmaxf(mm, sm[i]);
        sm[0] = mm;
    }
    __syncthreads();
    m = sm[0];
    float e = expf(v - m);
    float s = wave_reduce_sum(e);
    if (lane == 0) ss[wid] = s;
    __syncthreads();
    if (t == 0) {
        float tt = 0.f;
        for (int i = 0; i < 16; ++i) tt += ss[i];
        ss[0] = tt;
    }
    __syncthreads();
    out[t] = e / ss[0];
}

extern "C" void kernel_launch(void* const* d_in, const int* in_sizes, int n_in,
                              void* d_out, int out_size, void* d_ws, size_t ws_size,
                              hipStream_t stream) {
    const float* x = (const float*)d_in[0];
    const float* h[5]; const float* c[5];
    for (int k = 0; k < 5; ++k) {
        h[k] = (const float*)d_in[1 + 2 * k];
        c[k] = (const float*)d_in[2 + 2 * k];
    }
    const float* Wih[5]; const float* Whh[5]; const float* bih[5]; const float* bhh[5];
    for (int k = 0; k < 5; ++k) {
        Wih[k] = (const float*)d_in[11 + 4 * k];
        Whh[k] = (const float*)d_in[12 + 4 * k];
        bih[k] = (const float*)d_in[13 + 4 * k];
        bhh[k] = (const float*)d_in[14 + 4 * k];
    }
    const float* Wout = (const float*)d_in[31];
    const float* bout = (const float*)d_in[32];

    float* out = (float*)d_out;              // [0,1024) softmax out
    float* hn[5]; float* cn[5];
    for (int k = 0; k < 5; ++k) {
        hn[k] = out + 1024 + k * 4096;
        cn[k] = hn[k] + 2048;
    }

    float* ws  = (float*)d_ws;
    float* pre = ws;             // 5*8192 floats
    float* y   = ws + 5 * NGATE; // 5*1024 floats

    PreArgs pa;
    pa.x = x;
    pa.h0 = h[0]; pa.h1 = h[1]; pa.h2 = h[2]; pa.h3 = h[3]; pa.h4 = h[4];
    pa.Wih1 = Wih[0];
    pa.W0 = Whh[0]; pa.W1 = Whh[1]; pa.W2 = Whh[2]; pa.W3 = Whh[3]; pa.W4 = Whh[4];
    pa.bi0 = bih[0]; pa.bi1 = bih[1]; pa.bi2 = bih[2]; pa.bi3 = bih[3]; pa.bi4 = bih[4];
    pa.bh0 = bhh[0]; pa.bh1 = bhh[1]; pa.bh2 = bhh[2]; pa.bh3 = bhh[3]; pa.bh4 = bhh[4];
    pa.pre = pre;

    // All recurrent (Whh@h) GEMVs + Wih1@x: ~352 MB of streaming
    k_pre<<<2048, 256, 0, stream>>>(pa);

    // layer 1
    k_cell<<<8, 256, 0, stream>>>(pre, c[0], hn[0], cn[0]);
    k_head<<<256, 256, 0, stream>>>(Wout, bout, hn[0], y);
    // layer 2 (input y1)
    k_gatex<<<2048, 256, 0, stream>>>(Wih[1], y, nullptr, pre + NGATE);
    k_cell<<<8, 256, 0, stream>>>(pre + NGATE, c[1], hn[1], cn[1]);
    k_head<<<256, 256, 0, stream>>>(Wout, bout, hn[1], y + 1024);
    // layer 3 (input y2+y1)
    k_gatex<<<2048, 256, 0, stream>>>(Wih[2], y + 1024, y, pre + 2 * NGATE);
    k_cell<<<8, 256, 0, stream>>>(pre + 2 * NGATE, c[2], hn[2], cn[2]);
    k_head<<<256, 256, 0, stream>>>(Wout, bout, hn[2], y + 2048);
    // layer 4 (input y3+y2)
    k_gatex<<<2048, 256, 0, stream>>>(Wih[3], y + 2048, y + 1024, pre + 3 * NGATE);
    k_cell<<<8, 256, 0, stream>>>(pre + 3 * NGATE, c[3], hn[3], cn[3]);
    k_head<<<256, 256, 0, stream>>>(Wout, bout, hn[3], y + 3072);
    // layer 5 (input y4+y3)
    k_gatex<<<2048, 256, 0, stream>>>(Wih[4], y + 3072, y + 2048, pre + 4 * NGATE);
    k_cell<<<8, 256, 0, stream>>>(pre + 4 * NGATE, c[4], hn[4], cn[4]);
    k_head<<<256, 256, 0, stream>>>(Wout, bout, hn[4], y + 4096);
    // softmax -> out
    k_softmax<<<1, 1024, 0, stream>>>(y + 4096, out);
}

// Round 4
// 132.751 us; speedup vs baseline: 1.0783x; 1.0186x over previous
//
#include <hip/hip_runtime.h>
#include <math.h>

#define HSZ 2048
#define OSZ 1024
#define NGATE 8192  // 4*HSZ

typedef float f32x4 __attribute__((ext_vector_type(4)));

__device__ __forceinline__ float wave_reduce_sum(float v) {
    #pragma unroll
    for (int off = 32; off > 0; off >>= 1)
        v += __shfl_down(v, off, 64);
    return v;
}

struct PreArgs {
    const float* x;      // 1024
    const float* h0; const float* h1; const float* h2; const float* h3; const float* h4;
    const float* Wih1;   // 8192x1024
    const float* W0; const float* W1; const float* W2; const float* W3; const float* W4; // Whh_k 8192x2048
    const float* bi0; const float* bi1; const float* bi2; const float* bi3; const float* bi4;
    const float* bh0; const float* bh1; const float* bh2; const float* bh3; const float* bh4;
    float* pre;          // ws, 5*8192
};

#define DOT4(W, H) ((W).x * (H).x + (W).y * (H).y + (W).z * (H).z + (W).w * (H).w)

// Issue one 4KB weight chunk + matching 4KB h chunk (8 x dwordx4 per lane) as a
// single fire-and-forget asm burst. Compiler has no vm ops of its own in the
// loop, so manual vmcnt counts are exact.
#define ISSUE(J, WW, HH) do {                                                  \
    asm volatile(                                                              \
        "global_load_dwordx4 %0, %8, off\n\t"                                  \
        "global_load_dwordx4 %1, %8, off offset:1024\n\t"                      \
        "global_load_dwordx4 %2, %8, off offset:2048\n\t"                      \
        "global_load_dwordx4 %3, %8, off offset:3072\n\t"                      \
        "global_load_dwordx4 %4, %9, off\n\t"                                  \
        "global_load_dwordx4 %5, %9, off offset:1024\n\t"                      \
        "global_load_dwordx4 %6, %9, off offset:2048\n\t"                      \
        "global_load_dwordx4 %7, %9, off offset:3072\n\t"                      \
        : "=&v"(WW[0]), "=&v"(WW[1]), "=&v"(WW[2]), "=&v"(WW[3]),              \
          "=&v"(HH[0]), "=&v"(HH[1]), "=&v"(HH[2]), "=&v"(HH[3])               \
        : "v"(wsrc##J), "v"(hsrc##J));                                         \
} while (0)

// Counted wait + scheduling fence (rule 18: VALU consumers must not hoist
// above the inline-asm waitcnt).
#define VWAIT(N) do {                                                          \
    asm volatile("s_waitcnt vmcnt(" #N ")" ::: "memory");                      \
    __builtin_amdgcn_sched_barrier(0);                                         \
} while (0)

#define LAYER_OF(J) ((J) == 0 ? 0 : ((J) - 1) >> 1)

#define STEP(J, NW, WW, HH) do {                                               \
    VWAIT(NW);                                                                 \
    float s_ = DOT4(WW[0], HH[0]) + DOT4(WW[1], HH[1]) +                       \
               DOT4(WW[2], HH[2]) + DOT4(WW[3], HH[3]);                        \
    ls[LAYER_OF(J)] += s_;                                                     \
} while (0)

// 2048 blocks x 256 threads = 8192 waves; wave g computes gate row g for all 5
// layers via 11 chunks of 4KB, two-deep async pipeline, all loads in asm.
__global__ __launch_bounds__(256) void k_pre(PreArgs a) {
    const int g    = blockIdx.x * 4 + (threadIdx.x >> 6);  // 0..8191
    const int lane = threadIdx.x & 63;

    const float* Whh[5] = {a.W0, a.W1, a.W2, a.W3, a.W4};
    const float* hs[5]  = {a.h0, a.h1, a.h2, a.h3, a.h4};
    const float* bi[5]  = {a.bi0, a.bi1, a.bi2, a.bi3, a.bi4};
    const float* bh[5]  = {a.bh0, a.bh1, a.bh2, a.bh3, a.bh4};

    const size_t rw = (size_t)g * HSZ;
    const int lo = lane * 4;

    // chunk j=0: Wih1 row (4KB) vs x; j=1..10: layer (j-1)/2, half (j-1)&1
    const float* wsrc0  = a.Wih1 + (size_t)g * OSZ + lo;
    const float* hsrc0  = a.x + lo;
    const float* wsrc1  = Whh[0] + rw + 0    + lo;  const float* hsrc1  = hs[0] + 0    + lo;
    const float* wsrc2  = Whh[0] + rw + 1024 + lo;  const float* hsrc2  = hs[0] + 1024 + lo;
    const float* wsrc3  = Whh[1] + rw + 0    + lo;  const float* hsrc3  = hs[1] + 0    + lo;
    const float* wsrc4  = Whh[1] + rw + 1024 + lo;  const float* hsrc4  = hs[1] + 1024 + lo;
    const float* wsrc5  = Whh[2] + rw + 0    + lo;  const float* hsrc5  = hs[2] + 0    + lo;
    const float* wsrc6  = Whh[2] + rw + 1024 + lo;  const float* hsrc6  = hs[2] + 1024 + lo;
    const float* wsrc7  = Whh[3] + rw + 0    + lo;  const float* hsrc7  = hs[3] + 0    + lo;
    const float* wsrc8  = Whh[3] + rw + 1024 + lo;  const float* hsrc8  = hs[3] + 1024 + lo;
    const float* wsrc9  = Whh[4] + rw + 0    + lo;  const float* hsrc9  = hs[4] + 0    + lo;
    const float* wsrc10 = Whh[4] + rw + 1024 + lo;  const float* hsrc10 = hs[4] + 1024 + lo;

    float ls[5] = {0.f, 0.f, 0.f, 0.f, 0.f};
    f32x4 Wa[4], Ha[4], Wb[4], Hb[4];

    ISSUE(0, Wa, Ha);
    ISSUE(1, Wb, Hb);
    STEP(0, 8, Wa, Ha);  ISSUE(2, Wa, Ha);
    STEP(1, 8, Wb, Hb);  ISSUE(3, Wb, Hb);
    STEP(2, 8, Wa, Ha);  ISSUE(4, Wa, Ha);
    STEP(3, 8, Wb, Hb);  ISSUE(5, Wb, Hb);
    STEP(4, 8, Wa, Ha);  ISSUE(6, Wa, Ha);
    STEP(5, 8, Wb, Hb);  ISSUE(7, Wb, Hb);
    STEP(6, 8, Wa, Ha);  ISSUE(8, Wa, Ha);
    STEP(7, 8, Wb, Hb);  ISSUE(9, Wb, Hb);
    STEP(8, 8, Wa, Ha);  ISSUE(10, Wa, Ha);
    STEP(9, 8, Wb, Hb);
    STEP(10, 0, Wa, Ha);

    // interleaved wave reductions (5 independent chains share the 6 steps)
    #pragma unroll
    for (int off = 32; off > 0; off >>= 1) {
        #pragma unroll
        for (int k = 0; k < 5; ++k)
            ls[k] += __shfl_down(ls[k], off, 64);
    }
    if (lane == 0) {
        #pragma unroll
        for (int k = 0; k < 5; ++k)
            a.pre[k * NGATE + g] = ls[k] + bi[k][g] + bh[k][g];
    }
}

// gates[g] += Wih[g,:] · (ya [+ yb]) — one wave per row, 8192 rows
__global__ __launch_bounds__(256) void k_gatex(const float* __restrict__ Wih,
                                               const float* __restrict__ ya,
                                               const float* __restrict__ yb,
                                               float* __restrict__ gates) {
    const int w    = blockIdx.x * 4 + (threadIdx.x >> 6);  // 0..8191
    const int lane = threadIdx.x & 63;
    const float4* Wrow = (const float4*)(Wih + (size_t)w * OSZ);
    const float4* A = (const float4*)ya;
    const float4* B = (const float4*)yb;
    float sum = 0.f;
    #pragma unroll
    for (int it = 0; it < 4; ++it) {
        float4 wv = Wrow[it * 64 + lane];
        float4 av = A[it * 64 + lane];
        if (B) {
            float4 bv = B[it * 64 + lane];
            av.x += bv.x; av.y += bv.y; av.z += bv.z; av.w += bv.w;
        }
        sum += wv.x * av.x + wv.y * av.y + wv.z * av.z + wv.w * av.w;
    }
    sum = wave_reduce_sum(sum);
    if (lane == 0)
        gates[w] += sum;
}

// LSTM cell elementwise: 2048 threads
__global__ __launch_bounds__(256) void k_cell(const float* __restrict__ gates,
                                              const float* __restrict__ c_in,
                                              float* __restrict__ hn,
                                              float* __restrict__ cn) {
    const int j = blockIdx.x * 256 + threadIdx.x;  // grid 8 -> 0..2047
    float gi = gates[j];
    float gf = gates[HSZ + j];
    float gg = gates[2 * HSZ + j];
    float go = gates[3 * HSZ + j];
    float i = 1.f / (1.f + expf(-gi));
    float f = 1.f / (1.f + expf(-gf));
    float g = tanhf(gg);
    float o = 1.f / (1.f + expf(-go));
    float c = c_in[j];
    float cnew = f * c + i * g;
    float hnew = o * tanhf(cnew);
    cn[j] = cnew;
    hn[j] = hnew;
}

// y[j] = Wout[j,:] · h + bout[j] — one wave per row, 1024 rows
__global__ __launch_bounds__(256) void k_head(const float* __restrict__ Wout,
                                              const float* __restrict__ bout,
                                              const float* __restrict__ h,
                                              float* __restrict__ y) {
    const int w    = blockIdx.x * 4 + (threadIdx.x >> 6);  // 0..1023
    const int lane = threadIdx.x & 63;
    const float4* Wrow = (const float4*)(Wout + (size_t)w * HSZ);
    const float4* hv   = (const float4*)h;
    float sum = 0.f;
    #pragma unroll
    for (int it = 0; it < 8; ++it) {
        float4 wv = Wrow[it * 64 + lane];
        float4 h4 = hv[it * 64 + lane];
        sum += wv.x * h4.x + wv.y * h4.y + wv.z * h4.z + wv.w * h4.w;
    }
    sum = wave_reduce_sum(sum);
    if (lane == 0)
        y[w] = sum + bout[w];
}

// softmax over 1024 logits, single block of 1024 threads
__global__ __launch_bounds__(1024) void k_softmax(const float* __restrict__ logits,
                                                  float* __restrict__ out) {
    __shared__ float sm[16];
    __shared__ float ss[16];
    const int t = threadIdx.x;
    const int lane = t & 63;
    const int wid = t >> 6;
    float v = logits[t];
    float m = v;
    #pragma unroll
    for (int off = 32; off > 0; off >>= 1)
        m = fmaxf(m, __shfl_down(m, off, 64));
    if (lane == 0) sm[wid] = m;
    __syncthreads();
    if (t == 0) {
        float mm = sm[0];
        for (int i = 1; i < 16; ++i) mm = fmaxf(mm, sm[i]);
        sm[0] = mm;
    }
    __syncthreads();
    m = sm[0];
    float e = expf(v - m);
    float s = wave_reduce_sum(e);
    if (lane == 0) ss[wid] = s;
    __syncthreads();
    if (t == 0) {
        float tt = 0.f;
        for (int i = 0; i < 16; ++i) tt += ss[i];
        ss[0] = tt;
    }
    __syncthreads();
    out[t] = e / ss[0];
}

extern "C" void kernel_launch(void* const* d_in, const int* in_sizes, int n_in,
                              void* d_out, int out_size, void* d_ws, size_t ws_size,
                              hipStream_t stream) {
    const float* x = (const float*)d_in[0];
    const float* h[5]; const float* c[5];
    for (int k = 0; k < 5; ++k) {
        h[k] = (const float*)d_in[1 + 2 * k];
        c[k] = (const float*)d_in[2 + 2 * k];
    }
    const float* Wih[5]; const float* Whh[5]; const float* bih[5]; const float* bhh[5];
    for (int k = 0; k < 5; ++k) {
        Wih[k] = (const float*)d_in[11 + 4 * k];
        Whh[k] = (const float*)d_in[12 + 4 * k];
        bih[k] = (const float*)d_in[13 + 4 * k];
        bhh[k] = (const float*)d_in[14 + 4 * k];
    }
    const float* Wout = (const float*)d_in[31];
    const float* bout = (const float*)d_in[32];

    float* out = (float*)d_out;              // [0,1024) softmax out
    float* hn[5]; float* cn[5];
    for (int k = 0; k < 5; ++k) {
        hn[k] = out + 1024 + k * 4096;
        cn[k] = hn[k] + 2048;
    }

    float* ws  = (float*)d_ws;
    float* pre = ws;             // 5*8192 floats
    float* y   = ws + 5 * NGATE; // 5*1024 floats

    PreArgs pa;
    pa.x = x;
    pa.h0 = h[0]; pa.h1 = h[1]; pa.h2 = h[2]; pa.h3 = h[3]; pa.h4 = h[4];
    pa.Wih1 = Wih[0];
    pa.W0 = Whh[0]; pa.W1 = Whh[1]; pa.W2 = Whh[2]; pa.W3 = Whh[3]; pa.W4 = Whh[4];
    pa.bi0 = bih[0]; pa.bi1 = bih[1]; pa.bi2 = bih[2]; pa.bi3 = bih[3]; pa.bi4 = bih[4];
    pa.bh0 = bhh[0]; pa.bh1 = bhh[1]; pa.bh2 = bhh[2]; pa.bh3 = bhh[3]; pa.bh4 = bhh[4];
    pa.pre = pre;

    // All recurrent (Whh@h) GEMVs + Wih1@x: ~352 MB of streaming, deep async pipeline
    k_pre<<<2048, 256, 0, stream>>>(pa);

    // layer 1
    k_cell<<<8, 256, 0, stream>>>(pre, c[0], hn[0], cn[0]);
    k_head<<<256, 256, 0, stream>>>(Wout, bout, hn[0], y);
    // layer 2 (input y1)
    k_gatex<<<2048, 256, 0, stream>>>(Wih[1], y, nullptr, pre + NGATE);
    k_cell<<<8, 256, 0, stream>>>(pre + NGATE, c[1], hn[1], cn[1]);
    k_head<<<256, 256, 0, stream>>>(Wout, bout, hn[1], y + 1024);
    // layer 3 (input y2+y1)
    k_gatex<<<2048, 256, 0, stream>>>(Wih[2], y + 1024, y, pre + 2 * NGATE);
    k_cell<<<8, 256, 0, stream>>>(pre + 2 * NGATE, c[2], hn[2], cn[2]);
    k_head<<<256, 256, 0, stream>>>(Wout, bout, hn[2], y + 2048);
    // layer 4 (input y3+y2)
    k_gatex<<<2048, 256, 0, stream>>>(Wih[3], y + 2048, y + 1024, pre + 3 * NGATE);
    k_cell<<<8, 256, 0, stream>>>(pre + 3 * NGATE, c[3], hn[3], cn[3]);
    k_head<<<256, 256, 0, stream>>>(Wout, bout, hn[3], y + 3072);
    // layer 5 (input y4+y3)
    k_gatex<<<2048, 256, 0, stream>>>(Wih[4], y + 3072, y + 2048, pre + 4 * NGATE);
    k_cell<<<8, 256, 0, stream>>>(pre + 4 * NGATE, c[4], hn[4], cn[4]);
    k_head<<<256, 256, 0, stream>>>(Wout, bout, hn[4], y + 4096);
    // softmax -> out
    k_softmax<<<1, 1024, 0, stream>>>(y + 4096, out);
}